// Round 6
// baseline (508.599 us; speedup 1.0000x reference)
//
#include <hip/hip_runtime.h>
#include <hip/hip_bf16.h>
#include <cstddef>
#include <cstdint>

constexpr int Bn = 8, Cn = 256, Tn = 8192;
constexpr int NL = 3;          // layers / dilations (1,2,4)
constexpr int Kc = 768;        // K for both fused GEMMs (3*256)
constexpr float SLOPE = 0.1f;
constexpr int LP = 40;         // padded LDS row stride in u16 (80 B) — conflict-free

typedef unsigned short u16;
using bf8   = __attribute__((ext_vector_type(8))) short;  // 8 bf16 = 4 VGPRs
using f32x4 = __attribute__((ext_vector_type(4))) float;

__device__ __forceinline__ float lrelu(float v) { return v > 0.f ? v : SLOPE * v; }
__device__ __forceinline__ u16 f2bf(float f) {
    __hip_bfloat16 h = __float2bfloat16(f);
    return *reinterpret_cast<u16*>(&h);
}

// ---------------------------------------------------------------------------
// Weight prep (once): bf16 Wcat[l][o][s*256+c] from WC/WP/WF,
// bf16 WAp[l][o][tap*256+c] from WA[l][o][c][tap], bSum = bC+bP+bF,
// zero dummy row (ws re-poisoned each launch).
// ---------------------------------------------------------------------------
__global__ __launch_bounds__(256)
void k_wprep(const float* __restrict__ WC, const float* __restrict__ WP,
             const float* __restrict__ WF, const float* __restrict__ WA,
             const float* __restrict__ bC, const float* __restrict__ bP,
             const float* __restrict__ bF,
             u16* __restrict__ Wcat, u16* __restrict__ WAp, float* __restrict__ bSum,
             u16* __restrict__ zrow)
{
    if (blockIdx.x == 0) zrow[threadIdx.x] = 0;
    const int n1 = NL * Cn * Kc;
    for (int i = blockIdx.x * blockDim.x + threadIdx.x; i < n1;
         i += gridDim.x * blockDim.x) {
        int c = i % Cn;
        int s = (i / Cn) % 3;
        int o = (i / (3 * Cn)) % Cn;
        int l = i / (3 * Cn * Cn);
        size_t src = ((size_t)l * Cn + o) * Cn + c;
        float wc = (s == 0) ? WC[src] : (s == 1) ? WP[src] : WF[src];
        Wcat[i] = f2bf(wc);
        WAp[i] = f2bf(WA[src * 3 + s]);
    }
    for (int i = blockIdx.x * blockDim.x + threadIdx.x; i < NL * Cn;
         i += gridDim.x * blockDim.x)
        bSum[i] = bC[i] + bP[i] + bF[i];
}

// ---------------------------------------------------------------------------
// Layer-0 prep: xT[b][t][c] = bf16(lrelu(x[b][c][t]))  (transpose via LDS)
// ---------------------------------------------------------------------------
__global__ __launch_bounds__(256)
void k_prep(const float* __restrict__ x, u16* __restrict__ xT)
{
    __shared__ float s[64][65];
    const int b = blockIdx.z, c0 = blockIdx.y * 64, t0 = blockIdx.x * 64;
    const int tid = threadIdx.x;
    const float* xb = x + ((size_t)b * Cn + c0) * Tn + t0;

    int tt = tid & 63, c4 = tid >> 6;
    for (int cc = c4; cc < 64; cc += 4)
        s[cc][tt] = xb[(size_t)cc * Tn + tt];
    __syncthreads();

    int ccS = tid & 63, t4 = tid >> 6;
    u16* xTb = xT + ((size_t)b * Tn + t0) * Cn + c0;
    for (int t2 = t4; t2 < 64; t2 += 4)
        xTb[(size_t)t2 * Cn + ccS] = f2bf(lrelu(s[ccS][t2]));
}

// ---------------------------------------------------------------------------
// GEMM1: zT[b][t][o] = bf16(lrelu( sum_k Xcat[t][k]*Wcat[o][k] + bSum[o] ))
//   A = X (m=t) staged in LDS (padded rows, register-pipelined loads that
//   stay in flight across barriers). B = W (n=o) fragments loaded DIRECTLY
//   from global (only 2 o-tiles exist -> L2-hot).
// ---------------------------------------------------------------------------
__global__ __launch_bounds__(256)
void k_gemm1(const u16* __restrict__ xT, const float* __restrict__ d,
             const u16* __restrict__ Wl, const float* __restrict__ bS,
             float dil, u16* __restrict__ zT, const u16* __restrict__ zrow)
{
    __shared__ u16 sX[128 * LP];     // 10 KB, padded stride kills bank conflicts
    __shared__ int sRow[3][128];

    const int tid = threadIdx.x;
    const int b = blockIdx.z;
    const int t0 = blockIdx.x * 128;
    const int o0 = blockIdx.y * 128;

    if (tid < 128) {
        int t = t0 + tid;
        float dv = d[(size_t)b * Tn + t] * dil;
        int ip = (int)rintf((float)t - dv);   // round-half-even == jnp.round
        int iF = (int)rintf((float)t + dv);
        sRow[0][tid] = t;
        sRow[1][tid] = (ip >= 0) ? ip : -1;
        sRow[2][tid] = (iF < Tn) ? iF : -1;
    }
    __syncthreads();

    const int srow = tid >> 2;            // 0..63 (rows srow, srow+64)
    const int schunk = (tid & 3) * 8;     // u16 offset within 32
    const u16* xTb = xT + (size_t)b * Tn * Cn;

    const u16 *pr0[3], *pr1[3];
    #pragma unroll
    for (int s = 0; s < 3; ++s) {
        int r0 = sRow[s][srow], r1 = sRow[s][srow + 64];
        pr0[s] = (r0 >= 0) ? (xTb + (size_t)r0 * Cn + schunk) : (zrow + schunk);
        pr1[s] = (r1 >= 0) ? (xTb + (size_t)r1 * Cn + schunk) : (zrow + schunk);
    }

    const int lane = tid & 63, wv = tid >> 6;
    const int wm = (wv & 1) * 64;   // t-half
    const int wn = (wv >> 1) * 64;  // o-half
    const int lr = lane & 15, quad = lane >> 4;

    // W fragment row pointers (B-operand: n=lr row, k=quad*8..+7) — L2-hot
    const u16* wrow[4];
    #pragma unroll
    for (int ni = 0; ni < 4; ++ni)
        wrow[ni] = Wl + (size_t)(o0 + wn + ni * 16 + lr) * Kc + quad * 8;

    f32x4 acc[4][4] = {};
    uint4 xa = *(const uint4*)pr0[0];
    uint4 xb2 = *(const uint4*)pr1[0];

    #pragma unroll
    for (int kg = 0; kg < 24; ++kg) {
        __syncthreads();   // prev chunk's ds_reads done
        *(uint4*)(sX + srow * LP + schunk) = xa;
        *(uint4*)(sX + (srow + 64) * LP + schunk) = xb2;
        bf8 bg[4];
        #pragma unroll
        for (int ni = 0; ni < 4; ++ni)
            bg[ni] = *(const bf8*)(wrow[ni] + kg * 32);
        if (kg < 23) {      // prefetch next chunk; stays in flight across barrier
            int seg = (kg + 1) >> 3, off = ((kg + 1) & 7) * 32;
            xa  = *(const uint4*)(pr0[seg] + off);
            xb2 = *(const uint4*)(pr1[seg] + off);
        }
        __syncthreads();   // LDS chunk ready

        bf8 af[4];
        #pragma unroll
        for (int mi = 0; mi < 4; ++mi)
            af[mi] = *(const bf8*)(sX + (wm + mi * 16 + lr) * LP + quad * 8);
        #pragma unroll
        for (int mi = 0; mi < 4; ++mi)
            #pragma unroll
            for (int ni = 0; ni < 4; ++ni)
                acc[mi][ni] = __builtin_amdgcn_mfma_f32_16x16x32_bf16(
                    af[mi], bg[ni], acc[mi][ni], 0, 0, 0);
    }

    // epilogue: D row = m = t (quad*4+r), col = n = o (lr)
    float bias[4];
    #pragma unroll
    for (int ni = 0; ni < 4; ++ni) bias[ni] = bS[o0 + wn + ni * 16 + lr];
    u16* zTb = zT + (size_t)b * Tn * Cn;
    #pragma unroll
    for (int mi = 0; mi < 4; ++mi)
        #pragma unroll
        for (int r = 0; r < 4; ++r) {
            int t = t0 + wm + mi * 16 + quad * 4 + r;
            u16* row = zTb + (size_t)t * Cn + o0 + wn;
            #pragma unroll
            for (int ni = 0; ni < 4; ++ni)
                row[ni * 16 + lr] = f2bf(lrelu(acc[mi][ni][r] + bias[ni]));
        }
}

// ---------------------------------------------------------------------------
// GEMM2 (conv3 + residual + fused next-layer prep):
//   out[b][o][t] = sum_{tap,c} WAp[o][tap*256+c]*zT[t+tap-1][c] + bA[o] + xres
//   A = W (m=o) fragments direct from global (L2-hot); B = Z (n=t) via
//   padded LDS with register-pipelined staging.
// ---------------------------------------------------------------------------
__global__ __launch_bounds__(256)
void k_gemm2(const u16* __restrict__ zT, const u16* __restrict__ WAl,
             const float* __restrict__ bA, const float* __restrict__ xres,
             float* __restrict__ out, u16* __restrict__ xTn, int writeXT,
             const u16* __restrict__ zrow)
{
    __shared__ u16 sZ[128 * LP];     // 10 KB; reused by epilogue strips

    const int tid = threadIdx.x;
    const int b = blockIdx.z;
    const int t0 = blockIdx.x * 128;
    const int o0 = blockIdx.y * 128;

    const int srow = tid >> 2;
    const int schunk = (tid & 3) * 8;
    const int lane = tid & 63, wv = tid >> 6;
    const int wo = (wv & 1) * 64;   // o-half (m)
    const int wt = (wv >> 1) * 64;  // t-half (n)
    const int lr = lane & 15, quad = lane >> 4;

    const u16* zTb = zT + (size_t)b * Tn * Cn;
    const u16 *zr0[3], *zr1[3];
    #pragma unroll
    for (int tap = 0; tap < 3; ++tap) {
        int r0 = t0 + srow + tap - 1;
        int r1 = r0 + 64;
        zr0[tap] = (r0 >= 0 && r0 < Tn) ? (zTb + (size_t)r0 * Cn + schunk)
                                        : (zrow + schunk);
        zr1[tap] = (r1 >= 0 && r1 < Tn) ? (zTb + (size_t)r1 * Cn + schunk)
                                        : (zrow + schunk);
    }

    // W fragment row pointers (A-operand: m=lr row, k=quad*8..+7) — L2-hot
    const u16* wrow[4];
    #pragma unroll
    for (int mi = 0; mi < 4; ++mi)
        wrow[mi] = WAl + (size_t)(o0 + wo + mi * 16 + lr) * Kc + quad * 8;

    f32x4 acc[4][4] = {};
    uint4 za = *(const uint4*)zr0[0];
    uint4 zb2 = *(const uint4*)zr1[0];

    #pragma unroll
    for (int kg = 0; kg < 24; ++kg) {
        __syncthreads();
        *(uint4*)(sZ + srow * LP + schunk) = za;
        *(uint4*)(sZ + (srow + 64) * LP + schunk) = zb2;
        bf8 af[4];
        #pragma unroll
        for (int mi = 0; mi < 4; ++mi)
            af[mi] = *(const bf8*)(wrow[mi] + kg * 32);
        if (kg < 23) {
            int tap = (kg + 1) >> 3, off = ((kg + 1) & 7) * 32;
            za  = *(const uint4*)(zr0[tap] + off);
            zb2 = *(const uint4*)(zr1[tap] + off);
        }
        __syncthreads();

        bf8 bg[4];
        #pragma unroll
        for (int ni = 0; ni < 4; ++ni)
            bg[ni] = *(const bf8*)(sZ + (wt + ni * 16 + lr) * LP + quad * 8);
        #pragma unroll
        for (int mi = 0; mi < 4; ++mi)
            #pragma unroll
            for (int ni = 0; ni < 4; ++ni)
                acc[mi][ni] = __builtin_amdgcn_mfma_f32_16x16x32_bf16(
                    af[mi], bg[ni], acc[mi][ni], 0, 0, 0);
    }

    float biasv[4][4];
    #pragma unroll
    for (int mi = 0; mi < 4; ++mi) {
        float4 bb = *(const float4*)(bA + o0 + wo + mi * 16 + quad * 4);
        biasv[mi][0] = bb.x; biasv[mi][1] = bb.y; biasv[mi][2] = bb.z; biasv[mi][3] = bb.w;
    }

    if (writeXT) {
        // per-wave 16t x 64o strips, padded rows (72 u16 = 144B)
        u16* strip = sZ + wv * 1152;
        u16* xTb2 = xTn + (size_t)b * Tn * Cn;
        #pragma unroll
        for (int ni = 0; ni < 4; ++ni) {
            __syncthreads();   // staging/strip LDS free of readers
            #pragma unroll
            for (int mi = 0; mi < 4; ++mi) {
                ushort4 pk;
                #pragma unroll
                for (int r = 0; r < 4; ++r) {
                    int o = o0 + wo + mi * 16 + quad * 4 + r;
                    size_t idx = ((size_t)b * Cn + o) * Tn + t0 + wt + ni * 16 + lr;
                    float v = acc[mi][ni][r] + biasv[mi][r] + xres[idx];
                    out[idx] = v;
                    ((u16*)&pk)[r] = f2bf(lrelu(v));
                }
                *(ushort4*)(strip + lr * 72 + mi * 16 + quad * 4) = pk;
            }
            __syncthreads();   // strip writes visible
            #pragma unroll
            for (int it = 0; it < 2; ++it) {
                int tt = (lane >> 3) + it * 8;
                uint4 vv = *(const uint4*)(strip + tt * 72 + (lane & 7) * 8);
                *(uint4*)(xTb2 + (size_t)(t0 + wt + ni * 16 + tt) * Cn
                          + o0 + wo + (lane & 7) * 8) = vv;
            }
        }
    } else {
        #pragma unroll
        for (int mi = 0; mi < 4; ++mi)
            #pragma unroll
            for (int r = 0; r < 4; ++r) {
                int o = o0 + wo + mi * 16 + quad * 4 + r;
                size_t base = ((size_t)b * Cn + o) * Tn + t0 + wt;
                #pragma unroll
                for (int ni = 0; ni < 4; ++ni) {
                    size_t idx = base + ni * 16 + lr;
                    out[idx] = acc[mi][ni][r] + biasv[mi][r] + xres[idx];
                }
            }
    }
}

extern "C" void kernel_launch(void* const* d_in, const int* in_sizes, int n_in,
                              void* d_out, int out_size, void* d_ws, size_t ws_size,
                              hipStream_t stream)
{
    const float* x  = (const float*)d_in[0];
    const float* d  = (const float*)d_in[1];
    const float* WC = (const float*)d_in[2];
    const float* bC = (const float*)d_in[3];
    const float* WP = (const float*)d_in[4];
    const float* bP = (const float*)d_in[5];
    const float* WF = (const float*)d_in[6];
    const float* bF = (const float*)d_in[7];
    const float* WA = (const float*)d_in[8];
    const float* bA = (const float*)d_in[9];
    float* out = (float*)d_out;

    char* ws = (char*)d_ws;
    u16*   xT   = (u16*)(ws);                                   // 32 MiB
    u16*   zT   = (u16*)(ws + (size_t)Bn * Tn * Cn * 2);        // 32 MiB
    u16*   Wcat = (u16*)(ws + (size_t)2 * Bn * Tn * Cn * 2);    // 1.125 MiB
    u16*   WAp  = Wcat + (size_t)NL * Cn * Kc;                  // 1.125 MiB
    float* bSum = (float*)(WAp + (size_t)NL * Cn * Kc);         // 3 KiB
    u16*   zrow = (u16*)(bSum + NL * Cn);                       // 512 B zero row

    k_wprep<<<dim3(1024), dim3(256), 0, stream>>>(WC, WP, WF, WA, bC, bP, bF,
                                                  Wcat, WAp, bSum, zrow);

    dim3 gP(Tn / 64, Cn / 64, Bn);      // prep: 128 x 4 x 8
    dim3 gG(Tn / 128, Cn / 128, Bn);    // gemms: 64 x 2 x 8
    dim3 blk(256);

    k_prep<<<gP, blk, 0, stream>>>(x, xT);   // layer-0 input only

    const float dils[NL] = {1.f, 2.f, 4.f};
    const float* xcur = x;
    for (int i = 0; i < NL; ++i) {
        k_gemm1<<<gG, blk, 0, stream>>>(xT, d,
                                        Wcat + (size_t)i * Cn * Kc,
                                        bSum + (size_t)i * Cn,
                                        dils[i], zT, zrow);
        k_gemm2<<<gG, blk, 0, stream>>>(zT,
                                        WAp + (size_t)i * Cn * Kc,
                                        bA + (size_t)i * Cn,
                                        xcur, out, xT, (i < NL - 1) ? 1 : 0,
                                        zrow);
        xcur = out;   // residual read-then-write same element: in-place safe
    }
}